// Round 9
// baseline (777.643 us; speedup 1.0000x reference)
//
#include <hip/hip_runtime.h>
#include <hip/hip_fp16.h>
#include <cstddef>
#include <cstdint>

// ---------------------------------------------------------------------------
// SimpleHAN on MI355X — round 8:
//   - gat back to two-phase, but phase-2 gather has ZERO cross-lane ops:
//     each gather lane (16B of one row, head hd) recomputes alpha from
//     a_src[src*8+hd] (L2-hot 1.6MB) directly. Kills the 1.36M bank
//     conflicts that ds_bpermute alpha-broadcast caused in round 7.
//   - everything else unchanged.
// ---------------------------------------------------------------------------

#define HID        256
#define HEADS      8
#define NEG_SLOPE  0.2f

#define BSH     7          // bucket shift: 128 nodes per bucket
#define BNODES  128
#define MAXNB   512        // scan width (NB = 391 for N = 50000)
#define CH      2048       // edges per bin chunk

typedef __attribute__((ext_vector_type(8))) short short8v;
typedef __attribute__((ext_vector_type(4))) float float4v;

static __device__ __forceinline__ unsigned short f32_to_bf16(float v) {
    union { float f; unsigned u; } c; c.f = v;
    unsigned r = c.u + 0x7FFFu + ((c.u >> 16) & 1u);
    return (unsigned short)(r >> 16);
}
static __device__ __forceinline__ float bf16_to_f32(unsigned short b) {
    union { unsigned u; float f; } c; c.u = ((unsigned)b) << 16;
    return c.f;
}
static __device__ __forceinline__ void split_bf16(float v, unsigned short& hi, unsigned short& lo) {
    hi = f32_to_bf16(v);
    lo = f32_to_bf16(v - bf16_to_f32(hi));
}
static __device__ __forceinline__ void gload_lds16(const void* g, void* l) {
    __builtin_amdgcn_global_load_lds((const __attribute__((address_space(1))) void*)g,
                                     (__attribute__((address_space(3))) void*)l, 16, 0, 0);
}

// ------------------------- MFMA GEMM (bf16x3 split) ------------------------
// C[M,N] = (Ahi+Alo)[M,K] @ (Bthi+Btlo)[N,K]^T  (+bias)
// MODE 0: split bf16 hi/lo (+bias). MODE 1: fp16. MODE 2: fp32+bias+relu.
template<int MODE>
__global__ __launch_bounds__(256) void mfma_gemm_kernel(
    const unsigned short* __restrict__ Ahi, const unsigned short* __restrict__ Alo,
    const unsigned short* __restrict__ Bthi, const unsigned short* __restrict__ Btlo,
    const float* __restrict__ bias,
    unsigned short* __restrict__ Chi, unsigned short* __restrict__ Clo,
    __half* __restrict__ Cf16, float* __restrict__ Cf32,
    int M, int N, int K)
{
    __shared__ __align__(16) short lds[4 * 4096];  // 32 KB

    const int tid  = threadIdx.x;
    const int lane = tid & 63;
    const int w    = tid >> 6;
    const int wr   = w >> 1;
    const int wc   = w & 1;
    const int m0   = blockIdx.y * 128;
    const int n0   = blockIdx.x * 128;

    const unsigned short* sbase = (w == 0) ? Ahi : (w == 1) ? Alo : (w == 2) ? Bthi : Btlo;
    const int rowbase = (w < 2) ? m0 : n0;
    const int rowlim  = ((w < 2) ? M : N) - 1;

    float4v acc[4][4];
    #pragma unroll
    for (int i = 0; i < 4; ++i)
        #pragma unroll
        for (int j = 0; j < 4; ++j)
            acc[i][j] = (float4v){0.f, 0.f, 0.f, 0.f};

    const int kcl = lane >> 4;
    const int rl  = lane & 15;

    for (int k0 = 0; k0 < K; k0 += 32) {
        #pragma unroll
        for (int rh = 0; rh < 2; ++rh) {
            int row = rowbase + rh * 64 + lane;
            row = row > rowlim ? rowlim : row;
            const unsigned short* src = sbase + (size_t)row * K + k0;
            #pragma unroll
            for (int kc = 0; kc < 4; ++kc) {
                short* dst = &lds[w * 4096 + kc * 1024 + rh * 512];
                gload_lds16(src + kc * 8, dst);
            }
        }
        __syncthreads();

        short8v ahi[4], alo[4], bhi[4], blo[4];
        #pragma unroll
        for (int i = 0; i < 4; ++i) {
            int am = wr * 64 + i * 16 + rl;
            int bn = wc * 64 + i * 16 + rl;
            ahi[i] = *(const short8v*)&lds[0 * 4096 + kcl * 1024 + am * 8];
            alo[i] = *(const short8v*)&lds[1 * 4096 + kcl * 1024 + am * 8];
            bhi[i] = *(const short8v*)&lds[2 * 4096 + kcl * 1024 + bn * 8];
            blo[i] = *(const short8v*)&lds[3 * 4096 + kcl * 1024 + bn * 8];
        }
        #pragma unroll
        for (int i = 0; i < 4; ++i)
            #pragma unroll
            for (int j = 0; j < 4; ++j) {
                acc[i][j] = __builtin_amdgcn_mfma_f32_16x16x32_bf16(ahi[i], bhi[j], acc[i][j], 0, 0, 0);
                acc[i][j] = __builtin_amdgcn_mfma_f32_16x16x32_bf16(ahi[i], blo[j], acc[i][j], 0, 0, 0);
                acc[i][j] = __builtin_amdgcn_mfma_f32_16x16x32_bf16(alo[i], bhi[j], acc[i][j], 0, 0, 0);
            }
        __syncthreads();
    }

    const int cr = (lane >> 4) * 4;
    #pragma unroll
    for (int i = 0; i < 4; ++i) {
        #pragma unroll
        for (int r = 0; r < 4; ++r) {
            int row = m0 + wr * 64 + i * 16 + cr + r;
            if (row >= M) continue;
            #pragma unroll
            for (int j = 0; j < 4; ++j) {
                int col = n0 + wc * 64 + j * 16 + rl;
                float v = acc[i][j][r];
                if (bias) v += bias[col];
                if (MODE == 0) {
                    unsigned short h, l;
                    split_bf16(v, h, l);
                    Chi[(size_t)row * N + col] = h;
                    Clo[(size_t)row * N + col] = l;
                } else if (MODE == 1) {
                    Cf16[(size_t)row * N + col] = __float2half(v);
                } else {
                    Cf32[(size_t)row * N + col] = fmaxf(v, 0.f);
                }
            }
        }
    }
}

// ----------------------- unified prep (weights + x) ------------------------
__global__ void prep_kernel(
    const float* __restrict__ proj_W, const float* __restrict__ tut_W,
    const float* __restrict__ tdt_W, const float* __restrict__ cls_W1,
    unsigned short* __restrict__ pWthi, unsigned short* __restrict__ pWtlo,
    unsigned short* __restrict__ tWthi, unsigned short* __restrict__ tWtlo,
    unsigned short* __restrict__ dWthi, unsigned short* __restrict__ dWtlo,
    unsigned short* __restrict__ cWthi, unsigned short* __restrict__ cWtlo,
    const float* __restrict__ x,
    unsigned short* __restrict__ xhi, unsigned short* __restrict__ xlo, int count4x)
{
    const int tid = blockIdx.x * blockDim.x + threadIdx.x;
    const int stride = gridDim.x * blockDim.x;
    for (int idx = tid; idx < 327680; idx += stride) {
        unsigned short h, l;
        if (idx < 32768) {
            int k = idx >> 8, n = idx & 255;
            split_bf16(proj_W[idx], h, l);
            pWthi[n * 128 + k] = h; pWtlo[n * 128 + k] = l;
        } else if (idx < 163840) {
            int r = idx - 32768;
            int ly = r >> 16, rr = r & 65535;
            int k = rr >> 8, n = rr & 255;
            split_bf16(tut_W[r], h, l);
            tWthi[ly * 65536 + n * 256 + k] = h; tWtlo[ly * 65536 + n * 256 + k] = l;
        } else if (idx < 294912) {
            int r = idx - 163840;
            int ly = r >> 16, rr = r & 65535;
            int k = rr >> 8, n = rr & 255;
            split_bf16(tdt_W[r], h, l);
            dWthi[ly * 65536 + n * 256 + k] = h; dWtlo[ly * 65536 + n * 256 + k] = l;
        } else {
            int r = idx - 294912;
            int k = r >> 7, n = r & 127;
            split_bf16(cls_W1[r], h, l);
            cWthi[n * 256 + k] = h; cWtlo[n * 256 + k] = l;
        }
    }
    for (int i = tid; i < count4x; i += stride) {
        float4 v = reinterpret_cast<const float4*>(x)[i];
        ushort4 hh, ll;
        split_bf16(v.x, hh.x, ll.x);
        split_bf16(v.y, hh.y, ll.y);
        split_bf16(v.z, hh.z, ll.z);
        split_bf16(v.w, hh.w, ll.w);
        reinterpret_cast<ushort4*>(xhi)[i] = hh;
        reinterpret_cast<ushort4*>(xlo)[i] = ll;
    }
}

// ------------------------- attention dot products --------------------------
__global__ __launch_bounds__(256) void att_kernel(
    const __half* __restrict__ hW,
    const float* __restrict__ att_src, const float* __restrict__ att_dst,
    float* __restrict__ a_src, float* __restrict__ a_dst, int n_nodes)
{
    const int wave = threadIdx.x >> 6;
    const int lane = threadIdx.x & 63;
    const int n = blockIdx.x * 4 + wave;
    if (n >= n_nodes) return;

    const __half2* hp = reinterpret_cast<const __half2*>(&hW[(size_t)n * HID + lane * 4]);
    __half2 h01 = hp[0], h23 = hp[1];
    float hx = __low2float(h01), hy = __high2float(h01);
    float hz = __low2float(h23), hw = __high2float(h23);
    float4 s4 = *reinterpret_cast<const float4*>(&att_src[lane * 4]);
    float4 d4 = *reinterpret_cast<const float4*>(&att_dst[lane * 4]);
    float ps = hx * s4.x + hy * s4.y + hz * s4.z + hw * s4.w;
    float pd = hx * d4.x + hy * d4.y + hz * d4.z + hw * d4.w;
    #pragma unroll
    for (int off = 1; off < 8; off <<= 1) {
        ps += __shfl_xor(ps, off);
        pd += __shfl_xor(pd, off);
    }
    if ((lane & 7) == 0) {
        a_src[n * HEADS + (lane >> 3)] = ps;
        a_dst[n * HEADS + (lane >> 3)] = pd;
    }
}

// --------------- GAT two-phase; gather loop has no cross-lane ops ----------
// Phase 1: lane = (slot sl=lane>>3) x (head h1=lane&7); online (m,s) per
// (head,slot), butterfly-merged across slots (xor 8,16,32).
// Phase 2: half-wave hw=lane>>5 is edge parity; lane covers dims
// d0=(lane&31)*8, head hd=(lane&31)>>2. alpha recomputed per-lane from
// a_src (L2-hot) — no ds_bpermute in the loop. Final merge shfl_xor(32).
template<int OMODE>
__global__ __launch_bounds__(256) void gat_kernel(
    const __half* __restrict__ hW,
    const float* __restrict__ a_src, const float* __restrict__ a_dst,
    const int* __restrict__ row_ptr, const int* __restrict__ adj,
    const float* __restrict__ bias,
    const unsigned short* __restrict__ prevHi, const unsigned short* __restrict__ prevLo,
    const float* __restrict__ sem,
    unsigned short* __restrict__ outhi, unsigned short* __restrict__ outlo,
    int n_nodes)
{
    const int wave = threadIdx.x >> 6;
    const int lane = threadIdx.x & 63;
    const int n = blockIdx.x * 4 + wave;
    if (n >= n_nodes) return;

    const int beg = row_ptr[n];
    const int end = row_ptr[n + 1];
    const int h1 = lane & 7;           // phase-1 head
    const int sl = lane >> 3;          // phase-1 slot
    const int hw = lane >> 5;          // phase-2 edge parity
    const int l32 = lane & 31;
    const int d0 = l32 * 8;            // phase-2 dims d0..d0+7
    const int hd = l32 >> 2;           // phase-2 head

    const float adst1 = a_dst[n * HEADS + h1];

    // ---- phase 1: online max/sum per (head, slot) ----
    float m = -INFINITY, s = 0.f;
    for (int j = beg + sl; j < end; j += 8) {
        float e = a_src[adj[j] * HEADS + h1] + adst1;
        e = (e > 0.f) ? e : NEG_SLOPE * e;
        float mn = fmaxf(m, e);
        float t = (m > -INFINITY) ? s * __expf(m - mn) : 0.f;
        s = t + __expf(e - mn);
        m = mn;
    }
    #pragma unroll
    for (int off = 8; off < 64; off <<= 1) {
        float mo = __shfl_xor(m, off);
        float so = __shfl_xor(s, off);
        float mn = fmaxf(m, mo);
        float t1 = (m  > -INFINITY) ? s  * __expf(m  - mn) : 0.f;
        float t2 = (mo > -INFINITY) ? so * __expf(mo - mn) : 0.f;
        s = t1 + t2;
        m = mn;
    }

    // ---- redistribute to phase-2 layout (4 shfls, outside the loop) ----
    const float mh    = __shfl(m, hd);          // lane hd holds head hd (h1==hd)
    const float sh    = __shfl(s, hd);
    const float adst2 = __shfl(adst1, hd);
    const float inv   = 1.f / (sh + 1e-16f);

    // ---- phase 2: gather, alpha per-lane, 2 edges/iter, unroll 4 ----
    float acc[8];
    #pragma unroll
    for (int k = 0; k < 8; ++k) acc[k] = 0.f;

    for (int j = beg; j < end; j += 8) {
        #pragma unroll
        for (int it = 0; it < 4; ++it) {
            const int jj = j + it * 2 + hw;
            if (jj < end) {
                const int src = adj[jj];
                float e = a_src[src * HEADS + hd] + adst2;
                e = (e > 0.f) ? e : NEG_SLOPE * e;
                const float alpha = __expf(e - mh) * inv;
                float4 raw = *reinterpret_cast<const float4*>(&hW[(size_t)src * HID + d0]);
                __half2 v0 = *reinterpret_cast<__half2*>(&raw.x);
                __half2 v1 = *reinterpret_cast<__half2*>(&raw.y);
                __half2 v2 = *reinterpret_cast<__half2*>(&raw.z);
                __half2 v3 = *reinterpret_cast<__half2*>(&raw.w);
                acc[0] += alpha * __low2float(v0); acc[1] += alpha * __high2float(v0);
                acc[2] += alpha * __low2float(v1); acc[3] += alpha * __high2float(v1);
                acc[4] += alpha * __low2float(v2); acc[5] += alpha * __high2float(v2);
                acc[6] += alpha * __low2float(v3); acc[7] += alpha * __high2float(v3);
            }
        }
    }

    // merge the two edge-parity halves
    #pragma unroll
    for (int k = 0; k < 8; ++k) acc[k] += __shfl_xor(acc[k], 32);

    if (lane < 32) {
        float4 b0 = *reinterpret_cast<const float4*>(&bias[d0]);
        float4 b1 = *reinterpret_cast<const float4*>(&bias[d0 + 4]);
        float o[8];
        o[0] = acc[0] + b0.x; o[1] = acc[1] + b0.y;
        o[2] = acc[2] + b0.z; o[3] = acc[3] + b0.w;
        o[4] = acc[4] + b1.x; o[5] = acc[5] + b1.y;
        o[6] = acc[6] + b1.z; o[7] = acc[7] + b1.w;
        #pragma unroll
        for (int k = 0; k < 8; ++k)
            o[k] = (o[k] > 0.f) ? o[k] : expm1f(o[k]);

        if (OMODE == 1) {
            const float e0 = __expf(sem[0]);
            const float e1 = __expf(sem[1]);
            const float w0 = e0 / (e0 + e1);
            const float w1 = e1 / (e0 + e1);
            ushort4 ph0 = *reinterpret_cast<const ushort4*>(&prevHi[(size_t)n * HID + d0]);
            ushort4 ph1 = *reinterpret_cast<const ushort4*>(&prevHi[(size_t)n * HID + d0 + 4]);
            ushort4 pl0 = *reinterpret_cast<const ushort4*>(&prevLo[(size_t)n * HID + d0]);
            ushort4 pl1 = *reinterpret_cast<const ushort4*>(&prevLo[(size_t)n * HID + d0 + 4]);
            o[0] = w0 * (bf16_to_f32(ph0.x) + bf16_to_f32(pl0.x)) + w1 * o[0];
            o[1] = w0 * (bf16_to_f32(ph0.y) + bf16_to_f32(pl0.y)) + w1 * o[1];
            o[2] = w0 * (bf16_to_f32(ph0.z) + bf16_to_f32(pl0.z)) + w1 * o[2];
            o[3] = w0 * (bf16_to_f32(ph0.w) + bf16_to_f32(pl0.w)) + w1 * o[3];
            o[4] = w0 * (bf16_to_f32(ph1.x) + bf16_to_f32(pl1.x)) + w1 * o[4];
            o[5] = w0 * (bf16_to_f32(ph1.y) + bf16_to_f32(pl1.y)) + w1 * o[5];
            o[6] = w0 * (bf16_to_f32(ph1.z) + bf16_to_f32(pl1.z)) + w1 * o[6];
            o[7] = w0 * (bf16_to_f32(ph1.w) + bf16_to_f32(pl1.w)) + w1 * o[7];
        }

        ushort4 oh0, oh1, ol0, ol1;
        split_bf16(o[0], oh0.x, ol0.x); split_bf16(o[1], oh0.y, ol0.y);
        split_bf16(o[2], oh0.z, ol0.z); split_bf16(o[3], oh0.w, ol0.w);
        split_bf16(o[4], oh1.x, ol1.x); split_bf16(o[5], oh1.y, ol1.y);
        split_bf16(o[6], oh1.z, ol1.z); split_bf16(o[7], oh1.w, ol1.w);
        *reinterpret_cast<ushort4*>(&outhi[(size_t)n * HID + d0])     = oh0;
        *reinterpret_cast<ushort4*>(&outhi[(size_t)n * HID + d0 + 4]) = oh1;
        *reinterpret_cast<ushort4*>(&outlo[(size_t)n * HID + d0])     = ol0;
        *reinterpret_cast<ushort4*>(&outlo[(size_t)n * HID + d0 + 4]) = ol1;
    }
}

// ------------------- CSR build: bucketed counting sort ---------------------
__global__ __launch_bounds__(256) void bucket_count_kernel(
    const int* __restrict__ tut_dst, const int* __restrict__ tdt_dst,
    int* __restrict__ gcount, int E, int NB)
{
    __shared__ int hist[MAXNB];
    const int g = blockIdx.y;
    const int* dstp = g ? tdt_dst : tut_dst;
    for (int i = threadIdx.x; i < MAXNB; i += 256) hist[i] = 0;
    __syncthreads();
    for (int e = blockIdx.x * 256 + threadIdx.x; e < E; e += gridDim.x * 256)
        atomicAdd(&hist[dstp[e] >> BSH], 1);
    __syncthreads();
    for (int i = threadIdx.x; i < NB; i += 256) {
        int c = hist[i];
        if (c) atomicAdd(&gcount[g * NB + i], c);
    }
}

__global__ __launch_bounds__(512) void bucket_scan_kernel(
    const int* __restrict__ gcount, int* __restrict__ ebase, int* __restrict__ adjbase,
    int* __restrict__ rp0, int* __restrict__ rp1, int N, int E, int NB)
{
    __shared__ int sa[MAXNB], sb[MAXNB];
    const int t = threadIdx.x;
    for (int g = 0; g < 2; ++g) {
        int cnt = (t < NB) ? gcount[g * NB + t] : 0;
        int nodes = 0;
        if (t < NB) { int s = t << BSH; nodes = (N - s < BNODES) ? (N - s) : BNODES; }
        sa[t] = cnt;
        sb[t] = cnt + nodes;
        __syncthreads();
        for (int off = 1; off < MAXNB; off <<= 1) {
            int va = (t >= off) ? sa[t - off] : 0;
            int vb = (t >= off) ? sb[t - off] : 0;
            __syncthreads();
            sa[t] += va; sb[t] += vb;
            __syncthreads();
        }
        if (t < NB) {
            ebase[g * (NB + 1) + t + 1] = sa[t];
            adjbase[g * (NB + 1) + t + 1] = sb[t];
        }
        if (t == 0) { ebase[g * (NB + 1)] = 0; adjbase[g * (NB + 1)] = 0; }
        __syncthreads();
    }
    if (t == 0) { rp0[N] = E + N; rp1[N] = E + N; }
}

__global__ __launch_bounds__(256) void bucket_bin_kernel(
    const int* __restrict__ tut_ei, const int* __restrict__ tdt_ei,
    const int* __restrict__ ebase, int* __restrict__ gcursor,
    int2* __restrict__ ebuf, int E, int NB)
{
    __shared__ int lhist[MAXNB];
    __shared__ int lbase[MAXNB];
    __shared__ int loffs[MAXNB];
    __shared__ int2 spair[CH];
    __shared__ int saddr[CH];
    const int g = blockIdx.y;
    const int* ei = g ? tdt_ei : tut_ei;
    const int e0 = blockIdx.x * CH;
    const int cnt = (E - e0 < CH) ? (E - e0) : CH;

    for (int i = threadIdx.x; i < MAXNB; i += 256) lhist[i] = 0;
    __syncthreads();

    int myb[8], myrank[8], mysrc[8], mydst[8];
    int nmine = 0;
    #pragma unroll
    for (int k = 0; k < 8; ++k) {
        int idx = e0 + threadIdx.x + k * 256;
        if (idx < e0 + cnt) {
            int sv = ei[idx];
            int dv = ei[E + idx];
            int b = dv >> BSH;
            int r = atomicAdd(&lhist[b], 1);
            myb[nmine] = b; myrank[nmine] = r; mysrc[nmine] = sv; mydst[nmine] = dv;
            ++nmine;
        }
    }
    __syncthreads();
    loffs[threadIdx.x] = lhist[threadIdx.x];
    loffs[threadIdx.x + 256] = lhist[threadIdx.x + 256];
    __syncthreads();
    for (int off = 1; off < MAXNB; off <<= 1) {
        int i0 = threadIdx.x, i1 = threadIdx.x + 256;
        int v0 = (i0 >= off) ? loffs[i0 - off] : 0;
        int v1 = (i1 >= off) ? loffs[i1 - off] : 0;
        __syncthreads();
        loffs[i0] += v0; loffs[i1] += v1;
        __syncthreads();
    }
    for (int i = threadIdx.x; i < NB; i += 256) {
        int c = lhist[i];
        lbase[i] = c ? atomicAdd(&gcursor[g * NB + i], c) : 0;
    }
    __syncthreads();
    const int* eb = ebase + g * (NB + 1);
    for (int k = 0; k < nmine; ++k) {
        int b = myb[k];
        int sorted = loffs[b] - lhist[b] + myrank[k];
        spair[sorted] = make_int2(mysrc[k], mydst[k]);
        saddr[sorted] = eb[b] + lbase[b] + myrank[k];
    }
    __syncthreads();
    int2* out = ebuf + (size_t)g * E;
    for (int i = threadIdx.x; i < cnt; i += 256)
        out[saddr[i]] = spair[i];
}

__global__ __launch_bounds__(256) void bucket_csr_kernel(
    const int* __restrict__ gcount, const int* __restrict__ ebase,
    const int* __restrict__ adjbase, const int2* __restrict__ ebuf,
    int* __restrict__ rp0, int* __restrict__ rp1,
    int* __restrict__ adj0, int* __restrict__ adj1, int N, int E, int NB)
{
    __shared__ int hist[BNODES], scn[BNODES], cursor[BNODES];
    const int g = blockIdx.y;
    const int b = blockIdx.x;
    int* rp  = g ? rp1 : rp0;
    int* adj = g ? adj1 : adj0;
    const int cnt = gcount[g * NB + b];
    const int aB  = adjbase[g * (NB + 1) + b];
    const int node0 = b << BSH;
    const int nb = (N - node0 < BNODES) ? (N - node0) : BNODES;
    const int2* ep = ebuf + (size_t)g * E + ebase[g * (NB + 1) + b];
    const int t = threadIdx.x;

    if (t < BNODES) hist[t] = 0;
    __syncthreads();
    for (int e = t; e < cnt; e += 256)
        atomicAdd(&hist[ep[e].y - node0], 1);
    __syncthreads();
    if (t < BNODES) scn[t] = (t < nb) ? hist[t] + 1 : 0;
    __syncthreads();
    for (int off = 1; off < BNODES; off <<= 1) {
        int v = 0;
        if (t < BNODES && t >= off) v = scn[t - off];
        __syncthreads();
        if (t < BNODES) scn[t] += v;
        __syncthreads();
    }
    if (t < nb) {
        int s = scn[t] - hist[t] - 1;       // exclusive offset
        rp[node0 + t] = aB + s;
        adj[aB + s] = node0 + t;            // self-loop first
        cursor[t] = s + 1;
    }
    __syncthreads();
    for (int e = t; e < cnt; e += 256) {
        int2 pr = ep[e];
        int pos = atomicAdd(&cursor[pr.y - node0], 1);
        adj[aB + pos] = pr.x;
    }
}

// ------------------------------- classifier --------------------------------
__global__ __launch_bounds__(256) void cls2_kernel(
    const float* __restrict__ hc, const float* __restrict__ W2,
    const float* __restrict__ b2, float* __restrict__ out, int n_nodes)
{
    const int wave = threadIdx.x >> 6;
    const int lane = threadIdx.x & 63;
    const int n = blockIdx.x * 4 + wave;
    if (n >= n_nodes) return;
    float h0 = hc[(size_t)n * 128 + lane];
    float h1 = hc[(size_t)n * 128 + 64 + lane];
    float p0 = h0 * W2[lane * 2 + 0] + h1 * W2[(64 + lane) * 2 + 0];
    float p1 = h0 * W2[lane * 2 + 1] + h1 * W2[(64 + lane) * 2 + 1];
    #pragma unroll
    for (int off = 1; off < 64; off <<= 1) {
        p0 += __shfl_xor(p0, off);
        p1 += __shfl_xor(p1, off);
    }
    if (lane == 0) {
        out[(size_t)n * 2 + 0] = p0 + b2[0];
        out[(size_t)n * 2 + 1] = p1 + b2[1];
    }
}

// ---------------------------------------------------------------------------
extern "C" void kernel_launch(void* const* d_in, const int* in_sizes, int n_in,
                              void* d_out, int out_size, void* d_ws, size_t ws_size,
                              hipStream_t stream)
{
    const float* x        = (const float*)d_in[0];
    const int*   tut_ei   = (const int*)d_in[1];
    const int*   tdt_ei   = (const int*)d_in[2];
    const float* proj_W   = (const float*)d_in[3];
    const float* proj_b   = (const float*)d_in[4];
    const float* tut_W    = (const float*)d_in[5];
    const float* tut_asrc = (const float*)d_in[6];
    const float* tut_adst = (const float*)d_in[7];
    const float* tut_bias = (const float*)d_in[8];
    const float* tdt_W    = (const float*)d_in[9];
    const float* tdt_asrc = (const float*)d_in[10];
    const float* tdt_adst = (const float*)d_in[11];
    const float* tdt_bias = (const float*)d_in[12];
    const float* sem_att  = (const float*)d_in[13];
    const float* cls_W1   = (const float*)d_in[14];
    const float* cls_b1   = (const float*)d_in[15];
    const float* cls_W2   = (const float*)d_in[16];
    const float* cls_b2   = (const float*)d_in[17];

    const int IN_CH = 128;
    const int N = in_sizes[0] / IN_CH;     // 50000
    const int E = in_sizes[1] / 2;         // 800000
    const int NB = (N + BNODES - 1) >> BSH; // 391
    const size_t NH = (size_t)N * HID;
    const size_t NI = (size_t)N * IN_CH;

    // ------------------------ workspace layout ------------------------
    char* base = (char*)d_ws;
    size_t off = 0;
    auto alloc = [&](size_t bytes) -> void* {
        void* p = base + off;
        off = (off + bytes + 255) & ~(size_t)255;
        return p;
    };
    unsigned short* xhi  = (unsigned short*)alloc(NI * 2);
    unsigned short* xlo  = (unsigned short*)alloc(NI * 2);
    unsigned short* t2lo = (unsigned short*)alloc(NH * 2);
    unsigned short* h0hi = (unsigned short*)alloc(NH * 2);
    unsigned short* h0lo = (unsigned short*)alloc(NH * 2);
    unsigned short* l1hi = (unsigned short*)alloc(NH * 2);
    unsigned short* l1lo = (unsigned short*)alloc(NH * 2);
    __half*         hWf  = (__half*)alloc(NH * 2);           // 25.6MB; ebuf aliases
    float* a_src = (float*)alloc((size_t)N * HEADS * sizeof(float));
    float* a_dst = (float*)alloc((size_t)N * HEADS * sizeof(float));
    unsigned short* pWthi = (unsigned short*)alloc(256 * 128 * 2);
    unsigned short* pWtlo = (unsigned short*)alloc(256 * 128 * 2);
    unsigned short* tWthi = (unsigned short*)alloc(2 * 256 * 256 * 2);
    unsigned short* tWtlo = (unsigned short*)alloc(2 * 256 * 256 * 2);
    unsigned short* dWthi = (unsigned short*)alloc(2 * 256 * 256 * 2);
    unsigned short* dWtlo = (unsigned short*)alloc(2 * 256 * 256 * 2);
    unsigned short* cWthi = (unsigned short*)alloc(128 * 256 * 2);
    unsigned short* cWtlo = (unsigned short*)alloc(128 * 256 * 2);
    int* rp_tut  = (int*)alloc((size_t)(N + 1) * sizeof(int));
    int* adj_tut = (int*)alloc((size_t)(E + N) * sizeof(int));
    int* rp_tdt  = (int*)alloc((size_t)(N + 1) * sizeof(int));
    int* adj_tdt = (int*)alloc((size_t)(E + N) * sizeof(int));
    // gcount and gcursor in ONE block (alignment-safe single memset)
    int* gbuf    = (int*)alloc((size_t)4 * NB * sizeof(int));
    int* gcount  = gbuf;
    int* gcursor = gbuf + 2 * NB;
    int* ebase   = (int*)alloc((size_t)2 * (NB + 1) * sizeof(int));
    int* adjbase = (int*)alloc((size_t)2 * (NB + 1) * sizeof(int));
    (void)ws_size; (void)n_in; (void)out_size;

    int2* ebuf = (int2*)hWf;             // alias: ebuf dead before first GEMM writes hWf
    unsigned short* t2hi = xhi;          // alias: x dead after proj GEMM
    unsigned short* zhi  = l1hi;         // z written by fused TDT-L2 gat
    unsigned short* zlo  = l1lo;
    float*          hc   = (float*)hWf;

    const int nodeBlocks = (N + 3) / 4;

    // --------------------- CSR build (bucketed sort) ------------------
    hipMemsetAsync(gbuf, 0, (size_t)4 * NB * sizeof(int), stream);
    prep_kernel<<<1024, 256, 0, stream>>>(proj_W, tut_W, tdt_W, cls_W1,
                                          pWthi, pWtlo, tWthi, tWtlo, dWthi, dWtlo,
                                          cWthi, cWtlo, x, xhi, xlo, (int)(NI / 4));
    bucket_count_kernel<<<dim3(128, 2), 256, 0, stream>>>(tut_ei + E, tdt_ei + E, gcount, E, NB);
    bucket_scan_kernel<<<1, 512, 0, stream>>>(gcount, ebase, adjbase, rp_tut, rp_tdt, N, E, NB);
    bucket_bin_kernel<<<dim3((E + CH - 1) / CH, 2), 256, 0, stream>>>(
        tut_ei, tdt_ei, ebase, gcursor, ebuf, E, NB);
    bucket_csr_kernel<<<dim3(NB, 2), 256, 0, stream>>>(
        gcount, ebase, adjbase, ebuf, rp_tut, rp_tdt, adj_tut, adj_tdt, N, E, NB);

    const int gy = (N + 127) / 128;

    // ------------------------------ proj ------------------------------
    mfma_gemm_kernel<0><<<dim3(2, gy), 256, 0, stream>>>(
        xhi, xlo, pWthi, pWtlo, proj_b, h0hi, h0lo, nullptr, nullptr, N, HID, IN_CH);

    // ---------------------------- GAT layers --------------------------
    auto run_gemm_att = [&](const unsigned short* ahi, const unsigned short* alo,
                            const unsigned short* wthi, const unsigned short* wtlo,
                            const float* asrc_w, const float* adst_w) {
        mfma_gemm_kernel<1><<<dim3(2, gy), 256, 0, stream>>>(
            ahi, alo, wthi, wtlo, nullptr, nullptr, nullptr, hWf, nullptr, N, HID, HID);
        att_kernel<<<nodeBlocks, 256, 0, stream>>>(hWf, asrc_w, adst_w, a_src, a_dst, N);
    };

    const int WT = 256 * 256;
    const int AS = HEADS * (HID / HEADS);

    // TUT layer 1: h0 -> l1
    run_gemm_att(h0hi, h0lo, tWthi, tWtlo, tut_asrc, tut_adst);
    gat_kernel<0><<<nodeBlocks, 256, 0, stream>>>(
        hWf, a_src, a_dst, rp_tut, adj_tut, tut_bias,
        nullptr, nullptr, nullptr, l1hi, l1lo, N);
    // TUT layer 2: l1 -> t2
    run_gemm_att(l1hi, l1lo, tWthi + WT, tWtlo + WT, tut_asrc + AS, tut_adst + AS);
    gat_kernel<0><<<nodeBlocks, 256, 0, stream>>>(
        hWf, a_src, a_dst, rp_tut, adj_tut, tut_bias + HID,
        nullptr, nullptr, nullptr, t2hi, t2lo, N);
    // TDT layer 1: h0 -> l1
    run_gemm_att(h0hi, h0lo, dWthi, dWtlo, tdt_asrc, tdt_adst);
    gat_kernel<0><<<nodeBlocks, 256, 0, stream>>>(
        hWf, a_src, a_dst, rp_tdt, adj_tdt, tdt_bias,
        nullptr, nullptr, nullptr, l1hi, l1lo, N);
    // TDT layer 2 (fused semantic combine): z = w0*t2 + w1*elu(gat)
    run_gemm_att(l1hi, l1lo, dWthi + WT, dWtlo + WT, tdt_asrc + AS, tdt_adst + AS);
    gat_kernel<1><<<nodeBlocks, 256, 0, stream>>>(
        hWf, a_src, a_dst, rp_tdt, adj_tdt, tdt_bias + HID,
        t2hi, t2lo, sem_att, zhi, zlo, N);

    // --------------------------- classifier ---------------------------
    mfma_gemm_kernel<2><<<dim3(1, gy), 256, 0, stream>>>(
        zhi, zlo, cWthi, cWtlo, cls_b1, nullptr, nullptr, nullptr, hc, N, 128, HID);
    cls2_kernel<<<nodeBlocks, 256, 0, stream>>>(hc, cls_W2, cls_b2, (float*)d_out, N);
}

// Round 10
// 728.736 us; speedup vs baseline: 1.0671x; 1.0671x over previous
//
#include <hip/hip_runtime.h>
#include <hip/hip_fp16.h>
#include <cstddef>
#include <cstdint>

// ---------------------------------------------------------------------------
// SimpleHAN on MI355X — round 9:
//   - gat phase-2 REVERTED to round-3 measured-best form (83.6us): two-pass,
//     64-lane 8B gather, x4 unroll, per-lane alpha (8 lanes/head).
//   - TUT-L1 + TDT-L1 GEMMs merged into one N=512 dispatch (h0 read once);
//     epilogue splits cols into two fp16 outputs.
//   - ebuf packed int2 -> int (src<<7 | dst&127): half the staging traffic.
// ---------------------------------------------------------------------------

#define HID        256
#define HEADS      8
#define NEG_SLOPE  0.2f

#define BSH     7          // bucket shift: 128 nodes per bucket
#define BNODES  128
#define MAXNB   512        // scan width (NB = 391 for N = 50000)
#define CH      2048       // edges per bin chunk

typedef __attribute__((ext_vector_type(8))) short short8v;
typedef __attribute__((ext_vector_type(4))) float float4v;

static __device__ __forceinline__ unsigned short f32_to_bf16(float v) {
    union { float f; unsigned u; } c; c.f = v;
    unsigned r = c.u + 0x7FFFu + ((c.u >> 16) & 1u);
    return (unsigned short)(r >> 16);
}
static __device__ __forceinline__ float bf16_to_f32(unsigned short b) {
    union { unsigned u; float f; } c; c.u = ((unsigned)b) << 16;
    return c.f;
}
static __device__ __forceinline__ void split_bf16(float v, unsigned short& hi, unsigned short& lo) {
    hi = f32_to_bf16(v);
    lo = f32_to_bf16(v - bf16_to_f32(hi));
}
static __device__ __forceinline__ void gload_lds16(const void* g, void* l) {
    __builtin_amdgcn_global_load_lds((const __attribute__((address_space(1))) void*)g,
                                     (__attribute__((address_space(3))) void*)l, 16, 0, 0);
}

// ------------------------- MFMA GEMM (bf16x3 split) ------------------------
// C[M,N] = (Ahi+Alo)[M,K] @ (Bthi+Btlo)[N,K]^T  (+bias)
// MODE 0: split bf16 hi/lo (+bias). MODE 1: fp16 (col<256 -> Ca, else Cb,
// both row-stride 256). MODE 2: fp32+bias+relu.
template<int MODE>
__global__ __launch_bounds__(256) void mfma_gemm_kernel(
    const unsigned short* __restrict__ Ahi, const unsigned short* __restrict__ Alo,
    const unsigned short* __restrict__ Bthi, const unsigned short* __restrict__ Btlo,
    const float* __restrict__ bias,
    unsigned short* __restrict__ Chi, unsigned short* __restrict__ Clo,
    __half* __restrict__ Cf16a, __half* __restrict__ Cf16b, float* __restrict__ Cf32,
    int M, int N, int K)
{
    __shared__ __align__(16) short lds[4 * 4096];  // 32 KB

    const int tid  = threadIdx.x;
    const int lane = tid & 63;
    const int w    = tid >> 6;
    const int wr   = w >> 1;
    const int wc   = w & 1;
    const int m0   = blockIdx.y * 128;
    const int n0   = blockIdx.x * 128;

    const unsigned short* sbase = (w == 0) ? Ahi : (w == 1) ? Alo : (w == 2) ? Bthi : Btlo;
    const int rowbase = (w < 2) ? m0 : n0;
    const int rowlim  = ((w < 2) ? M : N) - 1;

    float4v acc[4][4];
    #pragma unroll
    for (int i = 0; i < 4; ++i)
        #pragma unroll
        for (int j = 0; j < 4; ++j)
            acc[i][j] = (float4v){0.f, 0.f, 0.f, 0.f};

    const int kcl = lane >> 4;
    const int rl  = lane & 15;

    for (int k0 = 0; k0 < K; k0 += 32) {
        #pragma unroll
        for (int rh = 0; rh < 2; ++rh) {
            int row = rowbase + rh * 64 + lane;
            row = row > rowlim ? rowlim : row;
            const unsigned short* src = sbase + (size_t)row * K + k0;
            #pragma unroll
            for (int kc = 0; kc < 4; ++kc) {
                short* dst = &lds[w * 4096 + kc * 1024 + rh * 512];
                gload_lds16(src + kc * 8, dst);
            }
        }
        __syncthreads();

        short8v ahi[4], alo[4], bhi[4], blo[4];
        #pragma unroll
        for (int i = 0; i < 4; ++i) {
            int am = wr * 64 + i * 16 + rl;
            int bn = wc * 64 + i * 16 + rl;
            ahi[i] = *(const short8v*)&lds[0 * 4096 + kcl * 1024 + am * 8];
            alo[i] = *(const short8v*)&lds[1 * 4096 + kcl * 1024 + am * 8];
            bhi[i] = *(const short8v*)&lds[2 * 4096 + kcl * 1024 + bn * 8];
            blo[i] = *(const short8v*)&lds[3 * 4096 + kcl * 1024 + bn * 8];
        }
        #pragma unroll
        for (int i = 0; i < 4; ++i)
            #pragma unroll
            for (int j = 0; j < 4; ++j) {
                acc[i][j] = __builtin_amdgcn_mfma_f32_16x16x32_bf16(ahi[i], bhi[j], acc[i][j], 0, 0, 0);
                acc[i][j] = __builtin_amdgcn_mfma_f32_16x16x32_bf16(ahi[i], blo[j], acc[i][j], 0, 0, 0);
                acc[i][j] = __builtin_amdgcn_mfma_f32_16x16x32_bf16(alo[i], bhi[j], acc[i][j], 0, 0, 0);
            }
        __syncthreads();
    }

    const int cr = (lane >> 4) * 4;
    #pragma unroll
    for (int i = 0; i < 4; ++i) {
        #pragma unroll
        for (int r = 0; r < 4; ++r) {
            int row = m0 + wr * 64 + i * 16 + cr + r;
            if (row >= M) continue;
            #pragma unroll
            for (int j = 0; j < 4; ++j) {
                int col = n0 + wc * 64 + j * 16 + rl;
                float v = acc[i][j][r];
                if (bias) v += bias[col];
                if (MODE == 0) {
                    unsigned short h, l;
                    split_bf16(v, h, l);
                    Chi[(size_t)row * N + col] = h;
                    Clo[(size_t)row * N + col] = l;
                } else if (MODE == 1) {
                    if (col < 256) Cf16a[(size_t)row * 256 + col] = __float2half(v);
                    else           Cf16b[(size_t)row * 256 + (col - 256)] = __float2half(v);
                } else {
                    Cf32[(size_t)row * N + col] = fmaxf(v, 0.f);
                }
            }
        }
    }
}

// ----------------------- unified prep (weights + x) ------------------------
// w1 = [tutW1^T ; tdtW1^T] as rows 0..511 (K=256 contiguous).
__global__ void prep_kernel(
    const float* __restrict__ proj_W, const float* __restrict__ tut_W,
    const float* __restrict__ tdt_W, const float* __restrict__ cls_W1,
    unsigned short* __restrict__ pWthi, unsigned short* __restrict__ pWtlo,
    unsigned short* __restrict__ w1hi,  unsigned short* __restrict__ w1lo,
    unsigned short* __restrict__ t2Whi, unsigned short* __restrict__ t2Wlo,
    unsigned short* __restrict__ d2Whi, unsigned short* __restrict__ d2Wlo,
    unsigned short* __restrict__ cWthi, unsigned short* __restrict__ cWtlo,
    const float* __restrict__ x,
    unsigned short* __restrict__ xhi, unsigned short* __restrict__ xlo, int count4x)
{
    const int tid = blockIdx.x * blockDim.x + threadIdx.x;
    const int stride = gridDim.x * blockDim.x;
    for (int idx = tid; idx < 327680; idx += stride) {
        unsigned short h, l;
        if (idx < 32768) {
            int k = idx >> 8, n = idx & 255;
            split_bf16(proj_W[idx], h, l);
            pWthi[n * 128 + k] = h; pWtlo[n * 128 + k] = l;
        } else if (idx < 163840) {
            int r = idx - 32768;
            int ly = r >> 16, rr = r & 65535;
            int k = rr >> 8, n = rr & 255;
            split_bf16(tut_W[r], h, l);
            if (ly == 0) { w1hi[n * 256 + k] = h;  w1lo[n * 256 + k] = l; }
            else         { t2Whi[n * 256 + k] = h; t2Wlo[n * 256 + k] = l; }
        } else if (idx < 294912) {
            int r = idx - 163840;
            int ly = r >> 16, rr = r & 65535;
            int k = rr >> 8, n = rr & 255;
            split_bf16(tdt_W[r], h, l);
            if (ly == 0) { w1hi[(256 + n) * 256 + k] = h; w1lo[(256 + n) * 256 + k] = l; }
            else         { d2Whi[n * 256 + k] = h;        d2Wlo[n * 256 + k] = l; }
        } else {
            int r = idx - 294912;
            int k = r >> 7, n = r & 127;
            split_bf16(cls_W1[r], h, l);
            cWthi[n * 256 + k] = h; cWtlo[n * 256 + k] = l;
        }
    }
    for (int i = tid; i < count4x; i += stride) {
        float4 v = reinterpret_cast<const float4*>(x)[i];
        ushort4 hh, ll;
        split_bf16(v.x, hh.x, ll.x);
        split_bf16(v.y, hh.y, ll.y);
        split_bf16(v.z, hh.z, ll.z);
        split_bf16(v.w, hh.w, ll.w);
        reinterpret_cast<ushort4*>(xhi)[i] = hh;
        reinterpret_cast<ushort4*>(xlo)[i] = ll;
    }
}

// ------------------------- attention dot products --------------------------
__global__ __launch_bounds__(256) void att_kernel(
    const __half* __restrict__ hW,
    const float* __restrict__ att_src, const float* __restrict__ att_dst,
    float* __restrict__ a_src, float* __restrict__ a_dst, int n_nodes)
{
    const int wave = threadIdx.x >> 6;
    const int lane = threadIdx.x & 63;
    const int n = blockIdx.x * 4 + wave;
    if (n >= n_nodes) return;

    const __half2* hp = reinterpret_cast<const __half2*>(&hW[(size_t)n * HID + lane * 4]);
    __half2 h01 = hp[0], h23 = hp[1];
    float hx = __low2float(h01), hy = __high2float(h01);
    float hz = __low2float(h23), hw = __high2float(h23);
    float4 s4 = *reinterpret_cast<const float4*>(&att_src[lane * 4]);
    float4 d4 = *reinterpret_cast<const float4*>(&att_dst[lane * 4]);
    float ps = hx * s4.x + hy * s4.y + hz * s4.z + hw * s4.w;
    float pd = hx * d4.x + hy * d4.y + hz * d4.z + hw * d4.w;
    #pragma unroll
    for (int off = 1; off < 8; off <<= 1) {
        ps += __shfl_xor(ps, off);
        pd += __shfl_xor(pd, off);
    }
    if ((lane & 7) == 0) {
        a_src[n * HEADS + (lane >> 3)] = ps;
        a_dst[n * HEADS + (lane >> 3)] = pd;
    }
}

// ---------- GAT two-pass (round-3 measured-best structure) + OMODE ---------
// Phase 1: lane = (head h1=lane&7) x (slot lane>>3), online (m,s), butterfly.
// Phase 2: lane covers dims lane*4..+3, head h2=lane>>3; per-edge alpha
// recomputed per lane; x4 unroll (4 edges in flight); 8B loads.
template<int OMODE>
__global__ __launch_bounds__(256) void gat_kernel(
    const __half* __restrict__ hW,
    const float* __restrict__ a_src, const float* __restrict__ a_dst,
    const int* __restrict__ row_ptr, const int* __restrict__ adj,
    const float* __restrict__ bias,
    const unsigned short* __restrict__ prevHi, const unsigned short* __restrict__ prevLo,
    const float* __restrict__ sem,
    unsigned short* __restrict__ outhi, unsigned short* __restrict__ outlo,
    int n_nodes)
{
    const int wave = threadIdx.x >> 6;
    const int lane = threadIdx.x & 63;
    const int n = blockIdx.x * 4 + wave;
    if (n >= n_nodes) return;

    const int beg = row_ptr[n];
    const int end = row_ptr[n + 1];
    const int h1 = lane & 7;
    const float adst1 = a_dst[n * HEADS + h1];

    // ---- phase 1 ----
    float m = -INFINITY, s = 0.f;
    for (int j = beg + (lane >> 3); j < end; j += 8) {
        float e = a_src[adj[j] * HEADS + h1] + adst1;
        e = (e > 0.f) ? e : NEG_SLOPE * e;
        float mn = fmaxf(m, e);
        float t = (m > -INFINITY) ? s * __expf(m - mn) : 0.f;
        s = t + __expf(e - mn);
        m = mn;
    }
    #pragma unroll
    for (int off = 8; off < 64; off <<= 1) {
        float mo = __shfl_xor(m, off);
        float so = __shfl_xor(s, off);
        float mn = fmaxf(m, mo);
        float t1 = (m  > -INFINITY) ? s  * __expf(m  - mn) : 0.f;
        float t2 = (mo > -INFINITY) ? so * __expf(mo - mn) : 0.f;
        s = t1 + t2;
        m = mn;
    }

    // ---- phase 2 ----
    const int h2 = lane >> 3;
    const float mh  = __shfl(m, h2);
    const float sh  = __shfl(s, h2);
    const float inv = 1.f / (sh + 1e-16f);
    const float adst2 = a_dst[n * HEADS + h2];
    const int lane4 = lane * 4;

    float4 acc = make_float4(0.f, 0.f, 0.f, 0.f);
    int j = beg;
    for (; j + 4 <= end; j += 4) {
        int s0 = adj[j + 0], s1 = adj[j + 1], s2 = adj[j + 2], s3 = adj[j + 3];
        float e0 = a_src[s0 * HEADS + h2] + adst2;
        float e1 = a_src[s1 * HEADS + h2] + adst2;
        float e2 = a_src[s2 * HEADS + h2] + adst2;
        float e3 = a_src[s3 * HEADS + h2] + adst2;
        e0 = (e0 > 0.f) ? e0 : NEG_SLOPE * e0;
        e1 = (e1 > 0.f) ? e1 : NEG_SLOPE * e1;
        e2 = (e2 > 0.f) ? e2 : NEG_SLOPE * e2;
        e3 = (e3 > 0.f) ? e3 : NEG_SLOPE * e3;
        float al0 = __expf(e0 - mh) * inv;
        float al1 = __expf(e1 - mh) * inv;
        float al2 = __expf(e2 - mh) * inv;
        float al3 = __expf(e3 - mh) * inv;
        const __half2* p0 = reinterpret_cast<const __half2*>(&hW[(size_t)s0 * HID + lane4]);
        const __half2* p1 = reinterpret_cast<const __half2*>(&hW[(size_t)s1 * HID + lane4]);
        const __half2* p2 = reinterpret_cast<const __half2*>(&hW[(size_t)s2 * HID + lane4]);
        const __half2* p3 = reinterpret_cast<const __half2*>(&hW[(size_t)s3 * HID + lane4]);
        __half2 a01 = p0[0], a23 = p0[1];
        __half2 b01 = p1[0], b23 = p1[1];
        __half2 c01 = p2[0], c23 = p2[1];
        __half2 d01 = p3[0], d23 = p3[1];
        acc.x += al0 * __low2float(a01); acc.y += al0 * __high2float(a01);
        acc.z += al0 * __low2float(a23); acc.w += al0 * __high2float(a23);
        acc.x += al1 * __low2float(b01); acc.y += al1 * __high2float(b01);
        acc.z += al1 * __low2float(b23); acc.w += al1 * __high2float(b23);
        acc.x += al2 * __low2float(c01); acc.y += al2 * __high2float(c01);
        acc.z += al2 * __low2float(c23); acc.w += al2 * __high2float(c23);
        acc.x += al3 * __low2float(d01); acc.y += al3 * __high2float(d01);
        acc.z += al3 * __low2float(d23); acc.w += al3 * __high2float(d23);
    }
    for (; j < end; ++j) {
        int src = adj[j];
        float e = a_src[src * HEADS + h2] + adst2;
        e = (e > 0.f) ? e : NEG_SLOPE * e;
        float alpha = __expf(e - mh) * inv;
        const __half2* p = reinterpret_cast<const __half2*>(&hW[(size_t)src * HID + lane4]);
        __half2 a01 = p[0], a23 = p[1];
        acc.x += alpha * __low2float(a01); acc.y += alpha * __high2float(a01);
        acc.z += alpha * __low2float(a23); acc.w += alpha * __high2float(a23);
    }

    float4 bv = *reinterpret_cast<const float4*>(&bias[lane4]);
    float4 o;
    o.x = acc.x + bv.x; o.y = acc.y + bv.y; o.z = acc.z + bv.z; o.w = acc.w + bv.w;
    o.x = (o.x > 0.f) ? o.x : expm1f(o.x);
    o.y = (o.y > 0.f) ? o.y : expm1f(o.y);
    o.z = (o.z > 0.f) ? o.z : expm1f(o.z);
    o.w = (o.w > 0.f) ? o.w : expm1f(o.w);

    if (OMODE == 1) {
        const float e0 = __expf(sem[0]);
        const float e1 = __expf(sem[1]);
        const float w0 = e0 / (e0 + e1);
        const float w1 = e1 / (e0 + e1);
        ushort4 ph = *reinterpret_cast<const ushort4*>(&prevHi[(size_t)n * HID + lane4]);
        ushort4 pl = *reinterpret_cast<const ushort4*>(&prevLo[(size_t)n * HID + lane4]);
        o.x = w0 * (bf16_to_f32(ph.x) + bf16_to_f32(pl.x)) + w1 * o.x;
        o.y = w0 * (bf16_to_f32(ph.y) + bf16_to_f32(pl.y)) + w1 * o.y;
        o.z = w0 * (bf16_to_f32(ph.z) + bf16_to_f32(pl.z)) + w1 * o.z;
        o.w = w0 * (bf16_to_f32(ph.w) + bf16_to_f32(pl.w)) + w1 * o.w;
    }

    ushort4 oh, ol;
    split_bf16(o.x, oh.x, ol.x);
    split_bf16(o.y, oh.y, ol.y);
    split_bf16(o.z, oh.z, ol.z);
    split_bf16(o.w, oh.w, ol.w);
    *reinterpret_cast<ushort4*>(&outhi[(size_t)n * HID + lane4]) = oh;
    *reinterpret_cast<ushort4*>(&outlo[(size_t)n * HID + lane4]) = ol;
}

// ------------------- CSR build: bucketed counting sort ---------------------
__global__ __launch_bounds__(256) void bucket_count_kernel(
    const int* __restrict__ tut_dst, const int* __restrict__ tdt_dst,
    int* __restrict__ gcount, int E, int NB)
{
    __shared__ int hist[MAXNB];
    const int g = blockIdx.y;
    const int* dstp = g ? tdt_dst : tut_dst;
    for (int i = threadIdx.x; i < MAXNB; i += 256) hist[i] = 0;
    __syncthreads();
    for (int e = blockIdx.x * 256 + threadIdx.x; e < E; e += gridDim.x * 256)
        atomicAdd(&hist[dstp[e] >> BSH], 1);
    __syncthreads();
    for (int i = threadIdx.x; i < NB; i += 256) {
        int c = hist[i];
        if (c) atomicAdd(&gcount[g * NB + i], c);
    }
}

__global__ __launch_bounds__(512) void bucket_scan_kernel(
    const int* __restrict__ gcount, int* __restrict__ ebase, int* __restrict__ adjbase,
    int* __restrict__ rp0, int* __restrict__ rp1, int N, int E, int NB)
{
    __shared__ int sa[MAXNB], sb[MAXNB];
    const int t = threadIdx.x;
    for (int g = 0; g < 2; ++g) {
        int cnt = (t < NB) ? gcount[g * NB + t] : 0;
        int nodes = 0;
        if (t < NB) { int s = t << BSH; nodes = (N - s < BNODES) ? (N - s) : BNODES; }
        sa[t] = cnt;
        sb[t] = cnt + nodes;
        __syncthreads();
        for (int off = 1; off < MAXNB; off <<= 1) {
            int va = (t >= off) ? sa[t - off] : 0;
            int vb = (t >= off) ? sb[t - off] : 0;
            __syncthreads();
            sa[t] += va; sb[t] += vb;
            __syncthreads();
        }
        if (t < NB) {
            ebase[g * (NB + 1) + t + 1] = sa[t];
            adjbase[g * (NB + 1) + t + 1] = sb[t];
        }
        if (t == 0) { ebase[g * (NB + 1)] = 0; adjbase[g * (NB + 1)] = 0; }
        __syncthreads();
    }
    if (t == 0) { rp0[N] = E + N; rp1[N] = E + N; }
}

// Pass B: packed staging entry = (src<<7) | (dst&127)
__global__ __launch_bounds__(256) void bucket_bin_kernel(
    const int* __restrict__ tut_ei, const int* __restrict__ tdt_ei,
    const int* __restrict__ ebase, int* __restrict__ gcursor,
    int* __restrict__ ebuf, int E, int NB)
{
    __shared__ int lhist[MAXNB];
    __shared__ int lbase[MAXNB];
    __shared__ int loffs[MAXNB];
    __shared__ int spair[CH];
    __shared__ int saddr[CH];
    const int g = blockIdx.y;
    const int* ei = g ? tdt_ei : tut_ei;
    const int e0 = blockIdx.x * CH;
    const int cnt = (E - e0 < CH) ? (E - e0) : CH;

    for (int i = threadIdx.x; i < MAXNB; i += 256) lhist[i] = 0;
    __syncthreads();

    int myb[8], myrank[8], mypk[8];
    int nmine = 0;
    #pragma unroll
    for (int k = 0; k < 8; ++k) {
        int idx = e0 + threadIdx.x + k * 256;
        if (idx < e0 + cnt) {
            int sv = ei[idx];
            int dv = ei[E + idx];
            int b = dv >> BSH;
            int r = atomicAdd(&lhist[b], 1);
            myb[nmine] = b; myrank[nmine] = r;
            mypk[nmine] = (sv << BSH) | (dv & (BNODES - 1));
            ++nmine;
        }
    }
    __syncthreads();
    loffs[threadIdx.x] = lhist[threadIdx.x];
    loffs[threadIdx.x + 256] = lhist[threadIdx.x + 256];
    __syncthreads();
    for (int off = 1; off < MAXNB; off <<= 1) {
        int i0 = threadIdx.x, i1 = threadIdx.x + 256;
        int v0 = (i0 >= off) ? loffs[i0 - off] : 0;
        int v1 = (i1 >= off) ? loffs[i1 - off] : 0;
        __syncthreads();
        loffs[i0] += v0; loffs[i1] += v1;
        __syncthreads();
    }
    for (int i = threadIdx.x; i < NB; i += 256) {
        int c = lhist[i];
        lbase[i] = c ? atomicAdd(&gcursor[g * NB + i], c) : 0;
    }
    __syncthreads();
    const int* eb = ebase + g * (NB + 1);
    for (int k = 0; k < nmine; ++k) {
        int b = myb[k];
        int sorted = loffs[b] - lhist[b] + myrank[k];
        spair[sorted] = mypk[k];
        saddr[sorted] = eb[b] + lbase[b] + myrank[k];
    }
    __syncthreads();
    int* out = ebuf + (size_t)g * E;
    for (int i = threadIdx.x; i < cnt; i += 256)
        out[saddr[i]] = spair[i];
}

__global__ __launch_bounds__(256) void bucket_csr_kernel(
    const int* __restrict__ gcount, const int* __restrict__ ebase,
    const int* __restrict__ adjbase, const int* __restrict__ ebuf,
    int* __restrict__ rp0, int* __restrict__ rp1,
    int* __restrict__ adj0, int* __restrict__ adj1, int N, int E, int NB)
{
    __shared__ int hist[BNODES], scn[BNODES], cursor[BNODES];
    const int g = blockIdx.y;
    const int b = blockIdx.x;
    int* rp  = g ? rp1 : rp0;
    int* adj = g ? adj1 : adj0;
    const int cnt = gcount[g * NB + b];
    const int aB  = adjbase[g * (NB + 1) + b];
    const int node0 = b << BSH;
    const int nb = (N - node0 < BNODES) ? (N - node0) : BNODES;
    const int* ep = ebuf + (size_t)g * E + ebase[g * (NB + 1) + b];
    const int t = threadIdx.x;

    if (t < BNODES) hist[t] = 0;
    __syncthreads();
    for (int e = t; e < cnt; e += 256)
        atomicAdd(&hist[ep[e] & (BNODES - 1)], 1);
    __syncthreads();
    if (t < BNODES) scn[t] = (t < nb) ? hist[t] + 1 : 0;
    __syncthreads();
    for (int off = 1; off < BNODES; off <<= 1) {
        int v = 0;
        if (t < BNODES && t >= off) v = scn[t - off];
        __syncthreads();
        if (t < BNODES) scn[t] += v;
        __syncthreads();
    }
    if (t < nb) {
        int s = scn[t] - hist[t] - 1;       // exclusive offset
        rp[node0 + t] = aB + s;
        adj[aB + s] = node0 + t;            // self-loop first
        cursor[t] = s + 1;
    }
    __syncthreads();
    for (int e = t; e < cnt; e += 256) {
        int p = ep[e];
        int pos = atomicAdd(&cursor[p & (BNODES - 1)], 1);
        adj[aB + pos] = p >> BSH;
    }
}

// ------------------------------- classifier --------------------------------
__global__ __launch_bounds__(256) void cls2_kernel(
    const float* __restrict__ hc, const float* __restrict__ W2,
    const float* __restrict__ b2, float* __restrict__ out, int n_nodes)
{
    const int wave = threadIdx.x >> 6;
    const int lane = threadIdx.x & 63;
    const int n = blockIdx.x * 4 + wave;
    if (n >= n_nodes) return;
    float h0 = hc[(size_t)n * 128 + lane];
    float h1 = hc[(size_t)n * 128 + 64 + lane];
    float p0 = h0 * W2[lane * 2 + 0] + h1 * W2[(64 + lane) * 2 + 0];
    float p1 = h0 * W2[lane * 2 + 1] + h1 * W2[(64 + lane) * 2 + 1];
    #pragma unroll
    for (int off = 1; off < 64; off <<= 1) {
        p0 += __shfl_xor(p0, off);
        p1 += __shfl_xor(p1, off);
    }
    if (lane == 0) {
        out[(size_t)n * 2 + 0] = p0 + b2[0];
        out[(size_t)n * 2 + 1] = p1 + b2[1];
    }
}

// ---------------------------------------------------------------------------
extern "C" void kernel_launch(void* const* d_in, const int* in_sizes, int n_in,
                              void* d_out, int out_size, void* d_ws, size_t ws_size,
                              hipStream_t stream)
{
    const float* x        = (const float*)d_in[0];
    const int*   tut_ei   = (const int*)d_in[1];
    const int*   tdt_ei   = (const int*)d_in[2];
    const float* proj_W   = (const float*)d_in[3];
    const float* proj_b   = (const float*)d_in[4];
    const float* tut_W    = (const float*)d_in[5];
    const float* tut_asrc = (const float*)d_in[6];
    const float* tut_adst = (const float*)d_in[7];
    const float* tut_bias = (const float*)d_in[8];
    const float* tdt_W    = (const float*)d_in[9];
    const float* tdt_asrc = (const float*)d_in[10];
    const float* tdt_adst = (const float*)d_in[11];
    const float* tdt_bias = (const float*)d_in[12];
    const float* sem_att  = (const float*)d_in[13];
    const float* cls_W1   = (const float*)d_in[14];
    const float* cls_b1   = (const float*)d_in[15];
    const float* cls_W2   = (const float*)d_in[16];
    const float* cls_b2   = (const float*)d_in[17];

    const int IN_CH = 128;
    const int N = in_sizes[0] / IN_CH;      // 50000
    const int E = in_sizes[1] / 2;          // 800000
    const int NB = (N + BNODES - 1) >> BSH; // 391
    const size_t NH = (size_t)N * HID;
    const size_t NI = (size_t)N * IN_CH;

    // ------------------------ workspace layout ------------------------
    char* base = (char*)d_ws;
    size_t off = 0;
    auto alloc = [&](size_t bytes) -> void* {
        void* p = base + off;
        off = (off + bytes + 255) & ~(size_t)255;
        return p;
    };
    unsigned short* xhi   = (unsigned short*)alloc(NI * 2);  // +xlo contiguous = t2hi
    unsigned short* xlo   = (unsigned short*)alloc(NI * 2);
    unsigned short* t2lo  = (unsigned short*)alloc(NH * 2);  // also hWb (L1 TDT fp16)
    unsigned short* h0hi  = (unsigned short*)alloc(NH * 2);  // also l1d hi
    unsigned short* h0lo  = (unsigned short*)alloc(NH * 2);  // also l1d lo
    unsigned short* l1thi = (unsigned short*)alloc(NH * 2);  // also z hi
    unsigned short* l1tlo = (unsigned short*)alloc(NH * 2);  // also z lo
    __half*         hWa   = (__half*)alloc(NH * 2);          // also ebuf, hc
    float* as1 = (float*)alloc((size_t)N * HEADS * sizeof(float));
    float* ad1 = (float*)alloc((size_t)N * HEADS * sizeof(float));
    float* as2 = (float*)alloc((size_t)N * HEADS * sizeof(float));
    float* ad2 = (float*)alloc((size_t)N * HEADS * sizeof(float));
    unsigned short* pWthi = (unsigned short*)alloc(256 * 128 * 2);
    unsigned short* pWtlo = (unsigned short*)alloc(256 * 128 * 2);
    unsigned short* w1hi  = (unsigned short*)alloc(512 * 256 * 2);
    unsigned short* w1lo  = (unsigned short*)alloc(512 * 256 * 2);
    unsigned short* t2Whi = (unsigned short*)alloc(256 * 256 * 2);
    unsigned short* t2Wlo = (unsigned short*)alloc(256 * 256 * 2);
    unsigned short* d2Whi = (unsigned short*)alloc(256 * 256 * 2);
    unsigned short* d2Wlo = (unsigned short*)alloc(256 * 256 * 2);
    unsigned short* cWthi = (unsigned short*)alloc(128 * 256 * 2);
    unsigned short* cWtlo = (unsigned short*)alloc(128 * 256 * 2);
    int* rp_tut  = (int*)alloc((size_t)(N + 1) * sizeof(int));
    int* adj_tut = (int*)alloc((size_t)(E + N) * sizeof(int));
    int* rp_tdt  = (int*)alloc((size_t)(N + 1) * sizeof(int));
    int* adj_tdt = (int*)alloc((size_t)(E + N) * sizeof(int));
    int* gbuf    = (int*)alloc((size_t)4 * NB * sizeof(int));
    int* gcount  = gbuf;
    int* gcursor = gbuf + 2 * NB;
    int* ebase   = (int*)alloc((size_t)2 * (NB + 1) * sizeof(int));
    int* adjbase = (int*)alloc((size_t)2 * (NB + 1) * sizeof(int));
    (void)ws_size; (void)n_in; (void)out_size;

    int* ebuf = (int*)hWa;                // dead before merged GEMM writes hWa
    __half* hWb = (__half*)t2lo;          // L1 TDT fp16; dead before t2lo written
    unsigned short* t2hi = xhi;           // x dead after proj GEMM
    unsigned short* l1dhi = h0hi;         // h0 dead after merged L1 GEMM
    unsigned short* l1dlo = h0lo;
    unsigned short* zhi = l1thi;          // l1t dead after TUT-L2 GEMM
    unsigned short* zlo = l1tlo;
    float* hc = (float*)hWa;              // hWa dead after TDT-L2 att/gat

    const int nodeBlocks = (N + 3) / 4;

    // --------------------- CSR build (bucketed sort) ------------------
    hipMemsetAsync(gbuf, 0, (size_t)4 * NB * sizeof(int), stream);
    prep_kernel<<<1024, 256, 0, stream>>>(proj_W, tut_W, tdt_W, cls_W1,
                                          pWthi, pWtlo, w1hi, w1lo, t2Whi, t2Wlo,
                                          d2Whi, d2Wlo, cWthi, cWtlo,
                                          x, xhi, xlo, (int)(NI / 4));
    bucket_count_kernel<<<dim3(128, 2), 256, 0, stream>>>(tut_ei + E, tdt_ei + E, gcount, E, NB);
    bucket_scan_kernel<<<1, 512, 0, stream>>>(gcount, ebase, adjbase, rp_tut, rp_tdt, N, E, NB);
    bucket_bin_kernel<<<dim3((E + CH - 1) / CH, 2), 256, 0, stream>>>(
        tut_ei, tdt_ei, ebase, gcursor, ebuf, E, NB);
    bucket_csr_kernel<<<dim3(NB, 2), 256, 0, stream>>>(
        gcount, ebase, adjbase, ebuf, rp_tut, rp_tdt, adj_tut, adj_tdt, N, E, NB);

    const int gy = (N + 127) / 128;
    const int AS = HEADS * (HID / HEADS);

    // ------------------------------ proj ------------------------------
    mfma_gemm_kernel<0><<<dim3(2, gy), 256, 0, stream>>>(
        xhi, xlo, pWthi, pWtlo, proj_b, h0hi, h0lo, nullptr, nullptr, nullptr,
        N, HID, IN_CH);

    // ------------- layer 1 (merged TUT+TDT GEMM, N=512) ---------------
    mfma_gemm_kernel<1><<<dim3(4, gy), 256, 0, stream>>>(
        h0hi, h0lo, w1hi, w1lo, nullptr, nullptr, nullptr, hWa, hWb, nullptr,
        N, 512, HID);
    att_kernel<<<nodeBlocks, 256, 0, stream>>>(hWa, tut_asrc, tut_adst, as1, ad1, N);
    att_kernel<<<nodeBlocks, 256, 0, stream>>>(hWb, tdt_asrc, tdt_adst, as2, ad2, N);
    gat_kernel<0><<<nodeBlocks, 256, 0, stream>>>(
        hWa, as1, ad1, rp_tut, adj_tut, tut_bias,
        nullptr, nullptr, nullptr, l1thi, l1tlo, N);
    gat_kernel<0><<<nodeBlocks, 256, 0, stream>>>(
        hWb, as2, ad2, rp_tdt, adj_tdt, tdt_bias,
        nullptr, nullptr, nullptr, l1dhi, l1dlo, N);

    // ---------------------------- TUT layer 2 -------------------------
    mfma_gemm_kernel<1><<<dim3(2, gy), 256, 0, stream>>>(
        l1thi, l1tlo, t2Whi, t2Wlo, nullptr, nullptr, nullptr, hWa, nullptr, nullptr,
        N, HID, HID);
    att_kernel<<<nodeBlocks, 256, 0, stream>>>(hWa, tut_asrc + AS, tut_adst + AS, as1, ad1, N);
    gat_kernel<0><<<nodeBlocks, 256, 0, stream>>>(
        hWa, as1, ad1, rp_tut, adj_tut, tut_bias + HID,
        nullptr, nullptr, nullptr, t2hi, t2lo, N);

    // ------------- TDT layer 2 (fused semantic combine) ---------------
    mfma_gemm_kernel<1><<<dim3(2, gy), 256, 0, stream>>>(
        l1dhi, l1dlo, d2Whi, d2Wlo, nullptr, nullptr, nullptr, hWa, nullptr, nullptr,
        N, HID, HID);
    att_kernel<<<nodeBlocks, 256, 0, stream>>>(hWa, tdt_asrc + AS, tdt_adst + AS, as2, ad2, N);
    gat_kernel<1><<<nodeBlocks, 256, 0, stream>>>(
        hWa, as2, ad2, rp_tdt, adj_tdt, tdt_bias + HID,
        t2hi, t2lo, sem_att, zhi, zlo, N);

    // --------------------------- classifier ---------------------------
    mfma_gemm_kernel<2><<<dim3(1, gy), 256, 0, stream>>>(
        zhi, zlo, cWthi, cWtlo, cls_b1, nullptr, nullptr, nullptr, nullptr, hc,
        N, 128, HID);
    cls2_kernel<<<nodeBlocks, 256, 0, stream>>>(hc, cls_W2, cls_b2, (float*)d_out, N);
}